// Round 15
// baseline (240.122 us; speedup 1.0000x reference)
//
#include <hip/hip_runtime.h>
#include <cstddef>
#include <cstdint>

namespace {

constexpr int S = 48;
constexpr int N = S * S;        // 2304 positions
constexpr int D = 512;          // d_model
constexpr int DK = 64;          // head dim
constexpr int B = 2;
constexpr int BH = 16;          // b*heads
constexpr int BHN = BH * N;     // 36864
constexpr int G_ARG = 6;        // argmax q-chunk split (384 q each = 6 tiles)
constexpr int CH_ARG = N / G_ARG;
constexpr int G_RC = 4;         // row/col chunk split (576 each = 9 tiles)
constexpr int CH_RC = N / G_RC;
constexpr float INV2S2 = 0.02f;     // 1/(2*sigma^2), sigma=5
// sqrt(SCALE * log2(e)) folded into each gaussian-table factor:
constexpr float FC = 0.42466080f;

typedef __attribute__((ext_vector_type(8))) short short8;
typedef __attribute__((ext_vector_type(8))) unsigned short ushort8v;
typedef __attribute__((ext_vector_type(4))) float f32x4;

#define MFMA(a, b, c) __builtin_amdgcn_mfma_f32_16x16x32_bf16((a), (b), (c), 0, 0, 0)

struct U3 { ushort a, b, c; };

// 3-way bf16 split: x ~= a + b + c (each RNE bf16), residual ~2^-26|x|
__device__ __forceinline__ U3 split3(float x)
{
    U3 u;
    uint b1 = __float_as_uint(x);
    uint r1 = (b1 + (0x7FFFu + ((b1 >> 16) & 1u))) & 0xFFFF0000u;
    u.a = (ushort)(r1 >> 16);
    float d1 = x - __uint_as_float(r1);                 // exact
    uint b2 = __float_as_uint(d1);
    uint r2 = (b2 + (0x7FFFu + ((b2 >> 16) & 1u))) & 0xFFFF0000u;
    u.b = (ushort)(r2 >> 16);
    float d2 = d1 - __uint_as_float(r2);                // exact
    uint b3 = __float_as_uint(d2);
    u.c = (ushort)((b3 + (0x7FFFu + ((b3 >> 16) & 1u))) >> 16);
    return u;
}

// Async-stage a 64x64 ushort tile global -> LDS via global_load_lds dwordx4.
// LDS dest is LINEAR (wave-uniform base + lane*16B, required by HW); the
// XOR swizzle is applied to the GLOBAL source address instead (involution),
// so frag_swz() reads reconstruct the original row data conflict-free.
__device__ __forceinline__ void stage_async(ushort* __restrict__ L,
                                            const ushort* __restrict__ g, int tid)
{
    #pragma unroll
    for (int it = 0; it < 2; it++) {
        int f = tid + 256 * it;
        int row = f >> 3, c8 = (f & 7) * 8;
        int srcoff = row * 64 + (c8 ^ ((row & 7) << 3));
        ushort* lbase = L + (size_t)(f & ~63) * 8;   // wave-uniform 16B-chunk base
        __builtin_amdgcn_global_load_lds(
            (const __attribute__((address_space(1))) void*)(g + srcoff),
            (__attribute__((address_space(3))) void*)lbase, 16, 0, 0);
    }
}

// Swizzled fragment read from a [64][64] tile staged by stage_async.
__device__ __forceinline__ short8 frag_swz(const ushort* __restrict__ L, int row, int k)
{
    int off = row * 64 + (k ^ ((row & 7) << 3));
    return *(const short8*)&L[off];
}

__device__ __forceinline__ short8 gfrag(const ushort* __restrict__ p, size_t off)
{
    return *(const short8*)&p[off];
}

// ---------------------------------------------------------------------------
// Kernel S: split inputs/weights to 3-way bf16 arrays.
// ---------------------------------------------------------------------------
__global__ __launch_bounds__(256)
void split_kernel(const float* __restrict__ qin, const float* __restrict__ kin,
                  const float* __restrict__ Wq, const float* __restrict__ Wk,
                  ushort* __restrict__ XQ1, ushort* __restrict__ XQ2, ushort* __restrict__ XQ3,
                  ushort* __restrict__ XK1, ushort* __restrict__ XK2, ushort* __restrict__ XK3,
                  ushort* __restrict__ W1, ushort* __restrict__ W2, ushort* __restrict__ W3)
{
    const int z = blockIdx.y;
    const int gid = blockIdx.x * 256 + threadIdx.x;
    const float* src;
    ushort *O1, *O2, *O3;
    size_t dst, soff;
    if (z < 2) {
        int m = gid >> 6, c = gid & 63;
        int b = (m >= N) ? 1 : 0;
        int npos = m - b * N;
        src = z ? kin : qin;
        if (z) { O1 = XK1; O2 = XK2; O3 = XK3; }
        else   { O1 = XQ1; O2 = XQ2; O3 = XQ3; }
        soff = (size_t)m * D + c * 8;
        dst = ((size_t)(b * 8 + (c >> 3)) * N + npos) * 64 + (c & 7) * 8;
    } else {
        if (gid >= 65536) return;
        int r = gid >> 6, c = gid & 63;
        int inp = r >> 9, n = r & 511;
        src = inp ? Wk : Wq;
        O1 = W1; O2 = W2; O3 = W3;
        soff = (size_t)n * D + c * 8;
        dst = ((size_t)(inp * 8 + (c >> 3)) * 512 + n) * 64 + (c & 7) * 8;
    }
    ushort8v u1, u2, u3;
    #pragma unroll
    for (int j = 0; j < 8; j++) {
        U3 t = split3(src[soff + j]);
        u1[j] = t.a; u2[j] = t.b; u3[j] = t.c;
    }
    *(ushort8v*)&O1[dst] = u1;
    *(ushort8v*)&O2[dst] = u2;
    *(ushort8v*)&O3[dst] = u3;
}

// ---------------------------------------------------------------------------
// Kernel A: MFMA projection (3-split, 6 products).  Async LDS staging.
// ---------------------------------------------------------------------------
__global__ __launch_bounds__(256)
void proj_kernel(const ushort* __restrict__ X1, const ushort* __restrict__ X2,
                 const ushort* __restrict__ X3, const ushort* __restrict__ Wp1,
                 const ushort* __restrict__ Wp2, const ushort* __restrict__ Wp3,
                 const float* __restrict__ bias,
                 ushort* __restrict__ O1, ushort* __restrict__ O2, ushort* __restrict__ O3)
{
    const int tid = threadIdx.x;
    const int lane = tid & 63, w = tid >> 6;
    const int wm = w >> 1, wn = w & 1;
    const int lg = lane >> 4, ln = lane & 15;
    const int hsel = blockIdx.x;          // head 0..7
    const int my = blockIdx.y;            // 0..71
    const int b = my / 36;
    const int npos0 = (my % 36) * 64;

    __shared__ alignas(16) ushort bufX[3][64 * 64];
    __shared__ alignas(16) ushort bufW[3][64 * 64];

    f32x4 acc[2][2];
    #pragma unroll
    for (int mt = 0; mt < 2; mt++)
        #pragma unroll
        for (int nt = 0; nt < 2; nt++) acc[mt][nt] = (f32x4){0.f, 0.f, 0.f, 0.f};

    for (int kh = 0; kh < 8; kh++) {
        stage_async(bufX[0], X1 + ((size_t)(b * 8 + kh) * N + npos0) * 64, tid);
        stage_async(bufX[1], X2 + ((size_t)(b * 8 + kh) * N + npos0) * 64, tid);
        stage_async(bufX[2], X3 + ((size_t)(b * 8 + kh) * N + npos0) * 64, tid);
        stage_async(bufW[0], Wp1 + ((size_t)kh * 512 + hsel * 64) * 64, tid);
        stage_async(bufW[1], Wp2 + ((size_t)kh * 512 + hsel * 64) * 64, tid);
        stage_async(bufW[2], Wp3 + ((size_t)kh * 512 + hsel * 64) * 64, tid);
        __syncthreads();

        short8 A[3][2][2], Bv[3][2][2];
        #pragma unroll
        for (int mt = 0; mt < 2; mt++)
            #pragma unroll
            for (int c = 0; c < 2; c++) {
                int row = 32 * wm + 16 * mt + ln, k = 32 * c + 8 * lg;
                A[0][mt][c] = frag_swz(bufX[0], row, k);
                A[1][mt][c] = frag_swz(bufX[1], row, k);
                A[2][mt][c] = frag_swz(bufX[2], row, k);
            }
        #pragma unroll
        for (int nt = 0; nt < 2; nt++)
            #pragma unroll
            for (int c = 0; c < 2; c++) {
                int row = 32 * wn + 16 * nt + ln, k = 32 * c + 8 * lg;
                Bv[0][nt][c] = frag_swz(bufW[0], row, k);
                Bv[1][nt][c] = frag_swz(bufW[1], row, k);
                Bv[2][nt][c] = frag_swz(bufW[2], row, k);
            }
        #pragma unroll
        for (int mt = 0; mt < 2; mt++)
            #pragma unroll
            for (int nt = 0; nt < 2; nt++) {
                f32x4 a = acc[mt][nt];
                a = MFMA(A[0][mt][0], Bv[0][nt][0], a);
                a = MFMA(A[0][mt][1], Bv[0][nt][1], a);
                a = MFMA(A[0][mt][0], Bv[1][nt][0], a);
                a = MFMA(A[0][mt][1], Bv[1][nt][1], a);
                a = MFMA(A[1][mt][0], Bv[0][nt][0], a);
                a = MFMA(A[1][mt][1], Bv[0][nt][1], a);
                a = MFMA(A[0][mt][0], Bv[2][nt][0], a);
                a = MFMA(A[0][mt][1], Bv[2][nt][1], a);
                a = MFMA(A[1][mt][0], Bv[1][nt][0], a);
                a = MFMA(A[1][mt][1], Bv[1][nt][1], a);
                a = MFMA(A[2][mt][0], Bv[0][nt][0], a);
                a = MFMA(A[2][mt][1], Bv[0][nt][1], a);
                acc[mt][nt] = a;
            }
        __syncthreads();
    }
    // epilogue: stage C through LDS, re-split3, coalesced per-head writes
    float* Cs = (float*)&bufX[0][0];      // [64][68]
    #pragma unroll
    for (int mt = 0; mt < 2; mt++)
        #pragma unroll
        for (int nt = 0; nt < 2; nt++)
            #pragma unroll
            for (int r = 0; r < 4; r++)
                Cs[(32 * wm + 16 * mt + 4 * lg + r) * 68 + 32 * wn + 16 * nt + ln] =
                    acc[mt][nt][r];
    __syncthreads();
    const int row = tid >> 2, c0 = (tid & 3) * 16;
    size_t dst = ((size_t)(b * 8 + hsel) * N + npos0 + row) * 64 + c0;
    #pragma unroll
    for (int half = 0; half < 2; half++) {
        ushort8v u1, u2, u3;
        #pragma unroll
        for (int j = 0; j < 8; j++) {
            int cc = c0 + half * 8 + j;
            float v = Cs[row * 68 + cc] + bias[hsel * 64 + cc];
            U3 t = split3(v);
            u1[j] = t.a; u2[j] = t.b; u3[j] = t.c;
        }
        *(ushort8v*)&O1[dst + half * 8] = u1;
        *(ushort8v*)&O2[dst + half * 8] = u2;
        *(ushort8v*)&O3[dst + half * 8] = u3;
    }
}

// ---------------------------------------------------------------------------
// Kernel B: argmax.  Block = 128 resident keys (4 waves x 32, frags in regs);
// streams 64-q tiles via async LDS staging (single buffer, 2 barriers/tile).
// 6 products.  grid (18, 16, 6).  Tie-break: lowest q.
// ---------------------------------------------------------------------------
__global__ __launch_bounds__(256)
void argmax_kernel(const ushort* __restrict__ Q1, const ushort* __restrict__ Q2,
                   const ushort* __restrict__ Q3, const ushort* __restrict__ K1,
                   const ushort* __restrict__ K2, const ushort* __restrict__ K3,
                   float* __restrict__ argV, int* __restrict__ argQ)
{
    const int bh = blockIdx.y;
    const int g  = blockIdx.z;
    const int tid = threadIdx.x;
    const int w = tid >> 6, lane = tid & 63;
    const int lg = lane >> 4, ln = lane & 15;
    const int kb = blockIdx.x * 128 + w * 32;   // wave's 32-key base
    const size_t hb = (size_t)bh * N;

    __shared__ alignas(16) ushort buf[3][64 * 64];

    short8 A[3][2][2];                    // [comp][mt][c], resident keys
    #pragma unroll
    for (int mt = 0; mt < 2; mt++)
        #pragma unroll
        for (int c = 0; c < 2; c++) {
            size_t off = (hb + kb + 16 * mt + ln) * 64 + 32 * c + 8 * lg;
            A[0][mt][c] = gfrag(K1, off);
            A[1][mt][c] = gfrag(K2, off);
            A[2][mt][c] = gfrag(K3, off);
        }

    float bestv[2][4];
    int   bestq[2][4];
    #pragma unroll
    for (int mt = 0; mt < 2; mt++)
        #pragma unroll
        for (int r = 0; r < 4; r++) { bestv[mt][r] = -3e38f; bestq[mt][r] = 0; }

    for (int qt = g * CH_ARG; qt < (g + 1) * CH_ARG; qt += 64) {
        stage_async(buf[0], Q1 + (hb + qt) * 64, tid);
        stage_async(buf[1], Q2 + (hb + qt) * 64, tid);
        stage_async(buf[2], Q3 + (hb + qt) * 64, tid);
        __syncthreads();
        #pragma unroll
        for (int nt = 0; nt < 4; nt++) {
            short8 Bv0[2], Bv1[2], Bv2[2];
            #pragma unroll
            for (int c = 0; c < 2; c++) {
                int row = 16 * nt + ln, k = 32 * c + 8 * lg;
                Bv0[c] = frag_swz(buf[0], row, k);
                Bv1[c] = frag_swz(buf[1], row, k);
                Bv2[c] = frag_swz(buf[2], row, k);
            }
            const int q = qt + 16 * nt + ln;
            #pragma unroll
            for (int mt = 0; mt < 2; mt++) {
                f32x4 acc = {0.f, 0.f, 0.f, 0.f};
                acc = MFMA(A[0][mt][0], Bv0[0], acc);
                acc = MFMA(A[0][mt][1], Bv0[1], acc);
                acc = MFMA(A[0][mt][0], Bv1[0], acc);
                acc = MFMA(A[0][mt][1], Bv1[1], acc);
                acc = MFMA(A[1][mt][0], Bv0[0], acc);
                acc = MFMA(A[1][mt][1], Bv0[1], acc);
                acc = MFMA(A[0][mt][0], Bv2[0], acc);
                acc = MFMA(A[0][mt][1], Bv2[1], acc);
                acc = MFMA(A[1][mt][0], Bv1[0], acc);
                acc = MFMA(A[1][mt][1], Bv1[1], acc);
                acc = MFMA(A[2][mt][0], Bv0[0], acc);
                acc = MFMA(A[2][mt][1], Bv0[1], acc);
                #pragma unroll
                for (int r = 0; r < 4; r++)
                    if (acc[r] > bestv[mt][r]) { bestv[mt][r] = acc[r]; bestq[mt][r] = q; }
            }
        }
        __syncthreads();
    }
    // reduce over the 16 q-lanes (ln); tie -> lower q
    #pragma unroll
    for (int d = 1; d < 16; d <<= 1) {
        #pragma unroll
        for (int mt = 0; mt < 2; mt++)
            #pragma unroll
            for (int r = 0; r < 4; r++) {
                float ov = __shfl_xor(bestv[mt][r], d);
                int   oq = __shfl_xor(bestq[mt][r], d);
                if (ov > bestv[mt][r] || (ov == bestv[mt][r] && oq < bestq[mt][r])) {
                    bestv[mt][r] = ov; bestq[mt][r] = oq;
                }
            }
    }
    if (ln == 0) {
        #pragma unroll
        for (int mt = 0; mt < 2; mt++)
            #pragma unroll
            for (int r = 0; r < 4; r++) {
                size_t o = (size_t)g * BHN + hb + kb + 16 * mt + 4 * lg + r;
                argV[o] = bestv[mt][r];
                argQ[o] = bestq[mt][r];
            }
    }
}

// ---------------------------------------------------------------------------
// Kernel C: row pass.  Block = 128 resident queries (4 waves x 32, B-frags in
// regs); streams 64-key tiles via async LDS staging (single buffer).  Side
// arrays preloaded once per chunk WITH inline argmax-combine (ascending g,
// strict >, lowest-q tie-break).  grid (18, 16, 4).
// ---------------------------------------------------------------------------
__global__ __launch_bounds__(256)
void rowpass_kernel(const ushort* __restrict__ Q1, const ushort* __restrict__ Q2,
                    const ushort* __restrict__ K1, const ushort* __restrict__ K2,
                    const float* __restrict__ argV, const int* __restrict__ argQ,
                    const float* __restrict__ value0,
                    float* __restrict__ rowPl, float* __restrict__ rowPa)
{
    const int bh = blockIdx.y, b = bh >> 3;
    const int g = blockIdx.z;
    const int tid = threadIdx.x;
    const int w = tid >> 6, lane = tid & 63;
    const int lg = lane >> 4, ln = lane & 15;
    const int qb = blockIdx.x * 128 + w * 32;   // wave's 32-query base
    const size_t hb = (size_t)bh * N;
    const int kbase = g * CH_RC;

    __shared__ alignas(16) ushort buf[2][64 * 64];
    __shared__ float F[48][49];
    __shared__ int ixi[CH_RC], iyi[CH_RC];
    __shared__ float v0s[CH_RC];

    for (int i = tid; i < 48 * 48; i += 256) {
        int a = i / 48, j = i % 48;
        float lj = -1.0f + (2.0f / 47.0f) * (float)j;
        float dd = lj - (float)a;
        F[a][j] = __expf(-dd * dd * INV2S2) * FC;
    }
    for (int i = tid; i < CH_RC; i += 256) {
        size_t key = hb + kbase + i;
        float bv = argV[key]; int bq = argQ[key];
        #pragma unroll
        for (int g2 = 1; g2 < G_ARG; g2++) {
            float v = argV[(size_t)g2 * BHN + key];
            int   q = argQ[(size_t)g2 * BHN + key];
            if (v > bv) { bv = v; bq = q; }
        }
        ixi[i] = bq % 48; iyi[i] = bq / 48;
        v0s[i] = value0[(size_t)b * N + kbase + i];
    }

    short8 Bq[2][2][2];                   // [comp][nt][c], resident queries
    int qx_[2], qy_[2];
    #pragma unroll
    for (int nt = 0; nt < 2; nt++) {
        #pragma unroll
        for (int c = 0; c < 2; c++) {
            size_t off = (hb + qb + 16 * nt + ln) * 64 + 32 * c + 8 * lg;
            Bq[0][nt][c] = gfrag(Q1, off);
            Bq[1][nt][c] = gfrag(Q2, off);
        }
        int qq = qb + 16 * nt + ln;
        qx_[nt] = qq % 48; qy_[nt] = qq / 48;
    }

    float l[2] = {0.f, 0.f}, a0[2] = {0.f, 0.f};

    for (int t = 0; t < CH_RC / 64; ++t) {
        stage_async(buf[0], K1 + (hb + kbase + t * 64) * 64, tid);
        stage_async(buf[1], K2 + (hb + kbase + t * 64) * 64, tid);
        __syncthreads();
        #pragma unroll
        for (int mt = 0; mt < 4; mt++) {
            short8 A0[2], A1[2];
            #pragma unroll
            for (int c = 0; c < 2; c++) {
                int row = 16 * mt + ln, k = 32 * c + 8 * lg;
                A0[c] = frag_swz(buf[0], row, k);
                A1[c] = frag_swz(buf[1], row, k);
            }
            #pragma unroll
            for (int nt = 0; nt < 2; nt++) {
                f32x4 acc = {0.f, 0.f, 0.f, 0.f};
                acc = MFMA(A0[0], Bq[0][nt][0], acc);
                acc = MFMA(A0[1], Bq[0][nt][1], acc);
                acc = MFMA(A0[0], Bq[1][nt][0], acc);
                acc = MFMA(A0[1], Bq[1][nt][1], acc);
                acc = MFMA(A1[0], Bq[0][nt][0], acc);
                acc = MFMA(A1[1], Bq[0][nt][1], acc);
                #pragma unroll
                for (int r = 0; r < 4; r++) {
                    int koff = t * 64 + 16 * mt + 4 * lg + r;
                    float tt = acc[r] * F[ixi[koff]][qx_[nt]] * F[iyi[koff]][qy_[nt]];
                    float e = __builtin_amdgcn_exp2f(tt);
                    l[nt]  += e;
                    a0[nt] += e * v0s[koff];
                }
            }
        }
        __syncthreads();
    }
    // sum over the 4 lg key-groups within the wave
    #pragma unroll
    for (int d = 16; d < 64; d <<= 1) {
        #pragma unroll
        for (int nt = 0; nt < 2; nt++) {
            l[nt]  += __shfl_xor(l[nt], d);
            a0[nt] += __shfl_xor(a0[nt], d);
        }
    }
    if (lane < 16) {
        #pragma unroll
        for (int nt = 0; nt < 2; nt++) {
            size_t o = (size_t)g * BHN + hb + qb + 16 * nt + ln;
            rowPl[o] = l[nt];
            rowPa[o] = a0[nt];
        }
    }
}

// rowfinal: den = sum_g l;  x0 = (sum_g a0) / den.
__global__ __launch_bounds__(256)
void rowfinal_kernel(const float* __restrict__ rowPl, const float* __restrict__ rowPa,
                     float* __restrict__ denomo, float* __restrict__ x0o)
{
    int i = blockIdx.x * 256 + threadIdx.x;
    if (i >= BHN) return;
    float L = 0.f, A = 0.f;
    #pragma unroll
    for (int g = 0; g < G_RC; g++) {
        L += rowPl[(size_t)g * BHN + i];
        A += rowPa[(size_t)g * BHN + i];
    }
    denomo[i] = L;
    x0o[i] = A / L;
}

// ---------------------------------------------------------------------------
// Kernel D: column pass.  Block = 128 resident keys (4 waves x 32, A-frags in
// regs); streams 64-q tiles via async LDS staging (single buffer).  Side
// arrays preloaded once per chunk; resident-key idx combined inline.
// grid (18, 16, 4).
// ---------------------------------------------------------------------------
__global__ __launch_bounds__(256)
void colpass_kernel(const ushort* __restrict__ Q1, const ushort* __restrict__ Q2,
                    const ushort* __restrict__ K1, const ushort* __restrict__ K2,
                    const float* __restrict__ argV, const int* __restrict__ argQ,
                    const float* __restrict__ value1,
                    const float* __restrict__ denomo, float* __restrict__ colP)
{
    const int bh = blockIdx.y, b = bh >> 3;
    const int g = blockIdx.z;
    const int tid = threadIdx.x;
    const int w = tid >> 6, lane = tid & 63;
    const int lg = lane >> 4, ln = lane & 15;
    const int kb = blockIdx.x * 128 + w * 32;   // wave's 32-key base
    const size_t hb = (size_t)bh * N;
    const int qbase = g * CH_RC;

    __shared__ alignas(16) ushort buf[2][64 * 64];
    __shared__ float F[48][49];
    __shared__ float wvs[CH_RC];
    __shared__ int qxs[CH_RC], qys[CH_RC];

    for (int i = tid; i < 48 * 48; i += 256) {
        int a = i / 48, j = i % 48;
        float lj = -1.0f + (2.0f / 47.0f) * (float)j;
        float dd = lj - (float)a;
        F[a][j] = __expf(-dd * dd * INV2S2) * FC;
    }
    for (int i = tid; i < CH_RC; i += 256) {
        int qg = qbase + i;
        wvs[i] = value1[(size_t)b * N + qg] / denomo[hb + qg];
        qxs[i] = qg % 48; qys[i] = qg / 48;
    }

    short8 A[2][2][2];                    // [comp][mt][c], resident keys
    int ixr[2][4], iyr[2][4];
    #pragma unroll
    for (int mt = 0; mt < 2; mt++) {
        #pragma unroll
        for (int c = 0; c < 2; c++) {
            size_t off = (hb + kb + 16 * mt + ln) * 64 + 32 * c + 8 * lg;
            A[0][mt][c] = gfrag(K1, off);
            A[1][mt][c] = gfrag(K2, off);
        }
        #pragma unroll
        for (int r = 0; r < 4; r++) {
            size_t key = hb + kb + 16 * mt + 4 * lg + r;
            float bv = argV[key]; int bq = argQ[key];
            #pragma unroll
            for (int g2 = 1; g2 < G_ARG; g2++) {
                float v = argV[(size_t)g2 * BHN + key];
                int   q = argQ[(size_t)g2 * BHN + key];
                if (v > bv) { bv = v; bq = q; }
            }
            ixr[mt][r] = bq % 48; iyr[mt][r] = bq / 48;
        }
    }

    float acc1[2][4] = {};

    for (int t = 0; t < CH_RC / 64; ++t) {
        stage_async(buf[0], Q1 + (hb + qbase + t * 64) * 64, tid);
        stage_async(buf[1], Q2 + (hb + qbase + t * 64) * 64, tid);
        __syncthreads();
        #pragma unroll
        for (int nt = 0; nt < 4; nt++) {
            short8 B0[2], B1[2];
            #pragma unroll
            for (int c = 0; c < 2; c++) {
                int row = 16 * nt + ln, k = 32 * c + 8 * lg;
                B0[c] = frag_swz(buf[0], row, k);
                B1[c] = frag_swz(buf[1], row, k);
            }
            const int qoff = t * 64 + 16 * nt + ln;
            const int qx = qxs[qoff], qy = qys[qoff];
            const float wv = wvs[qoff];
            #pragma unroll
            for (int mt = 0; mt < 2; mt++) {
                f32x4 acc = {0.f, 0.f, 0.f, 0.f};
                acc = MFMA(A[0][mt][0], B0[0], acc);
                acc = MFMA(A[0][mt][1], B0[1], acc);
                acc = MFMA(A[0][mt][0], B1[0], acc);
                acc = MFMA(A[0][mt][1], B1[1], acc);
                acc = MFMA(A[1][mt][0], B0[0], acc);
                acc = MFMA(A[1][mt][1], B0[1], acc);
                #pragma unroll
                for (int r = 0; r < 4; r++) {
                    float tt = acc[r] * F[ixr[mt][r]][qx] * F[iyr[mt][r]][qy];
                    acc1[mt][r] += __builtin_amdgcn_exp2f(tt) * wv;
                }
            }
        }
        __syncthreads();
    }
    // sum over the 16 q-lanes (ln)
    #pragma unroll
    for (int d = 1; d < 16; d <<= 1)
        #pragma unroll
        for (int mt = 0; mt < 2; mt++)
            #pragma unroll
            for (int r = 0; r < 4; r++)
                acc1[mt][r] += __shfl_xor(acc1[mt][r], d);
    if (ln == 0) {
        #pragma unroll
        for (int mt = 0; mt < 2; mt++)
            #pragma unroll
            for (int r = 0; r < 4; r++)
                colP[(size_t)g * BHN + hb + kb + 16 * mt + 4 * lg + r] = acc1[mt][r];
    }
}

// colfinal: x1 = sum_g partials.
__global__ __launch_bounds__(256)
void colfinal_kernel(const float* __restrict__ colP, float* __restrict__ x1o)
{
    int i = blockIdx.x * 256 + threadIdx.x;
    if (i >= BHN) return;
    float X = 0.f;
    #pragma unroll
    for (int g = 0; g < G_RC; g++) X += colP[(size_t)g * BHN + i];
    x1o[i] = X;
}

// ---------------------------------------------------------------------------
// Kernel E: out[b,q,k] = (1/8) * sum_h x0[b,h,q] * x1[b,h,k]   (float4 stores)
// ---------------------------------------------------------------------------
__global__ __launch_bounds__(256)
void outer_kernel(const float* __restrict__ x0, const float* __restrict__ x1,
                  float* __restrict__ out)
{
    const int b = blockIdx.z;
    const int q0 = blockIdx.y * 32, k0 = blockIdx.x * 32;
    __shared__ float x0s[8][32];
    __shared__ float x1s[8][32];
    const int tid = threadIdx.x;
    {
        int hh = tid >> 5, i = tid & 31;
        x0s[hh][i] = x0[(size_t)(b * 8 + hh) * N + q0 + i];
        x1s[hh][i] = x1[(size_t)(b * 8 + hh) * N + k0 + i];
    }
    __syncthreads();
    const int row = tid >> 3, c4 = (tid & 7) * 4;
    float4 a = {0.f, 0.f, 0.f, 0.f};
    #pragma unroll
    for (int hh = 0; hh < 8; hh++) {
        float s = x0s[hh][row];
        a.x += s * x1s[hh][c4 + 0];
        a.y += s * x1s[hh][c4 + 1];
        a.z += s * x1s[hh][c4 + 2];
        a.w += s * x1s[hh][c4 + 3];
    }
    a.x *= 0.125f; a.y *= 0.125f; a.z *= 0.125f; a.w *= 0.125f;
    *(float4*)(out + (size_t)b * N * N + (size_t)(q0 + row) * N + k0 + c4) = a;
}

} // namespace

extern "C" void kernel_launch(void* const* d_in, const int* in_sizes, int n_in,
                              void* d_out, int out_size, void* d_ws, size_t ws_size,
                              hipStream_t stream) {
    const float* qin = (const float*)d_in[0];
    const float* kin = (const float*)d_in[1];
    const float* v0  = (const float*)d_in[2];
    const float* v1  = (const float*)d_in[3];
    const float* Wq  = (const float*)d_in[4];
    const float* bq  = (const float*)d_in[5];
    const float* Wk  = (const float*)d_in[6];
    const float* bk  = (const float*)d_in[7];
    float* out = (float*)d_out;

    // d_out = exactly 9 split-array slots (18*ARR bytes = out bytes):
    //   A.1 [0,3ARR)   : Q1..Q3 proj outputs (live to colpass)
    //   A.2 [3ARR,6ARR): Xk input splits (dead after projK) -> partials/den
    //   B   [6ARR,9ARR): Xq input splits (dead after projQ) -> K1..K3 outputs
    const size_t ARR = (size_t)BH * N * DK;   // 2359296 ushorts
    ushort* out_u = (ushort*)d_out;
    ushort* Q1  = out_u;
    ushort* Q2  = out_u + ARR;
    ushort* Q3  = out_u + 2 * ARR;
    ushort* XK1 = out_u + 3 * ARR;
    ushort* XK2 = out_u + 4 * ARR;
    ushort* XK3 = out_u + 5 * ARR;
    ushort* XQ1 = out_u + 6 * ARR;
    ushort* XQ2 = out_u + 7 * ARR;
    ushort* XQ3 = out_u + 8 * ARR;
    ushort* K1 = XQ1;  ushort* K2 = XQ2;  ushort* K3 = XQ3;  // projK overwrites Xq

    float* tail = (float*)XK1;                 // A.2 reuse after projK (14.15 MB)
    float* argV  = tail;                                  // [G_ARG][BHN]
    int*   argQ  = (int*)(argV + (size_t)G_ARG * BHN);    // [G_ARG][BHN]
    float* rowPl = (float*)(argQ + (size_t)G_ARG * BHN);  // [G_RC][BHN]
    float* rowPa = rowPl + (size_t)G_RC * BHN;            // [G_RC][BHN]
    float* colP  = rowPa + (size_t)G_RC * BHN;            // [G_RC][BHN]
    float* den   = colP + (size_t)G_RC * BHN;             // [BHN]

    // ws: W splits (3 MB) + x0/x1 (outer's inputs; must not live in d_out)
    const size_t WARR = (size_t)2 * 512 * 512;     // 524288 ushorts per comp
    ushort* W1 = (ushort*)d_ws;
    ushort* W2 = W1 + WARR;
    ushort* W3 = W2 + WARR;
    float* x0b = (float*)(W3 + WARR);
    float* x1b = x0b + (size_t)BHN;

    const size_t WSLICE = (size_t)8 * 512 * 64;    // per-input W-split stride

    const int RB = (BHN + 255) / 256;   // 144 blocks for elementwise finalizers

    split_kernel   <<<dim3(1152, 3),       dim3(256), 0, stream>>>(qin, kin, Wq, Wk,
                                                                   XQ1, XQ2, XQ3,
                                                                   XK1, XK2, XK3,
                                                                   W1, W2, W3);
    proj_kernel    <<<dim3(8, 72),         dim3(256), 0, stream>>>(XQ1, XQ2, XQ3,
                                                                   W1, W2, W3, bq,
                                                                   Q1, Q2, Q3);
    proj_kernel    <<<dim3(8, 72),         dim3(256), 0, stream>>>(XK1, XK2, XK3,
                                                                   W1 + WSLICE, W2 + WSLICE,
                                                                   W3 + WSLICE, bk,
                                                                   K1, K2, K3);
    argmax_kernel  <<<dim3(18, 16, G_ARG), dim3(256), 0, stream>>>(Q1, Q2, Q3, K1, K2, K3,
                                                                   argV, argQ);
    rowpass_kernel <<<dim3(18, 16, G_RC),  dim3(256), 0, stream>>>(Q1, Q2, K1, K2,
                                                                   argV, argQ, v0,
                                                                   rowPl, rowPa);
    rowfinal_kernel<<<dim3(RB),            dim3(256), 0, stream>>>(rowPl, rowPa, den, x0b);
    colpass_kernel <<<dim3(18, 16, G_RC),  dim3(256), 0, stream>>>(Q1, Q2, K1, K2,
                                                                   argV, argQ, v1,
                                                                   den, colP);
    colfinal_kernel<<<dim3(RB),            dim3(256), 0, stream>>>(colP, x1b);
    outer_kernel   <<<dim3(72, 72, 2),     dim3(256), 0, stream>>>(x0b, x1b, out);
}

// Round 16
// 230.302 us; speedup vs baseline: 1.0426x; 1.0426x over previous
//
#include <hip/hip_runtime.h>
#include <cstddef>
#include <cstdint>

namespace {

constexpr int S = 48;
constexpr int N = S * S;        // 2304 positions
constexpr int D = 512;          // d_model
constexpr int DK = 64;          // head dim
constexpr int B = 2;
constexpr int BH = 16;          // b*heads
constexpr int BHN = BH * N;     // 36864
constexpr int G_ARG = 6;        // argmax q-chunk split (384 q each = 6 tiles)
constexpr int CH_ARG = N / G_ARG;
constexpr int G_RC = 6;         // row/col chunk split (384 each = 6 tiles)
constexpr int CH_RC = N / G_RC;
constexpr float INV2S2 = 0.02f;     // 1/(2*sigma^2), sigma=5
// sqrt(SCALE * log2(e)) folded into each gaussian-table factor:
constexpr float FC = 0.42466080f;

typedef __attribute__((ext_vector_type(8))) short short8;
typedef __attribute__((ext_vector_type(8))) unsigned short ushort8v;
typedef __attribute__((ext_vector_type(4))) float f32x4;

#define MFMA(a, b, c) __builtin_amdgcn_mfma_f32_16x16x32_bf16((a), (b), (c), 0, 0, 0)

struct U3 { ushort a, b, c; };

// 3-way bf16 split: x ~= a + b + c (each RNE bf16), residual ~2^-26|x|
__device__ __forceinline__ U3 split3(float x)
{
    U3 u;
    uint b1 = __float_as_uint(x);
    uint r1 = (b1 + (0x7FFFu + ((b1 >> 16) & 1u))) & 0xFFFF0000u;
    u.a = (ushort)(r1 >> 16);
    float d1 = x - __uint_as_float(r1);                 // exact
    uint b2 = __float_as_uint(d1);
    uint r2 = (b2 + (0x7FFFu + ((b2 >> 16) & 1u))) & 0xFFFF0000u;
    u.b = (ushort)(r2 >> 16);
    float d2 = d1 - __uint_as_float(r2);                // exact
    uint b3 = __float_as_uint(d2);
    u.c = (ushort)((b3 + (0x7FFFu + ((b3 >> 16) & 1u))) >> 16);
    return u;
}

// Async-stage a 64x64 ushort tile global -> LDS via global_load_lds dwordx4.
// LDS dest is LINEAR (wave-uniform base + lane*16B, required by HW); the
// XOR swizzle is applied to the GLOBAL source address instead (involution),
// so frag_swz() reads reconstruct the original row data conflict-free.
__device__ __forceinline__ void stage_async(ushort* __restrict__ L,
                                            const ushort* __restrict__ g, int tid)
{
    #pragma unroll
    for (int it = 0; it < 2; it++) {
        int f = tid + 256 * it;
        int row = f >> 3, c8 = (f & 7) * 8;
        int srcoff = row * 64 + (c8 ^ ((row & 7) << 3));
        ushort* lbase = L + (size_t)(f & ~63) * 8;   // wave-uniform 16B-chunk base
        __builtin_amdgcn_global_load_lds(
            (const __attribute__((address_space(1))) void*)(g + srcoff),
            (__attribute__((address_space(3))) void*)lbase, 16, 0, 0);
    }
}

// Swizzled fragment read from a [64][64] tile staged by stage_async.
__device__ __forceinline__ short8 frag_swz(const ushort* __restrict__ L, int row, int k)
{
    int off = row * 64 + (k ^ ((row & 7) << 3));
    return *(const short8*)&L[off];
}

__device__ __forceinline__ short8 gfrag(const ushort* __restrict__ p, size_t off)
{
    return *(const short8*)&p[off];
}

// ---------------------------------------------------------------------------
// Kernel S: split inputs/weights to 3-way bf16 arrays.
// ---------------------------------------------------------------------------
__global__ __launch_bounds__(256)
void split_kernel(const float* __restrict__ qin, const float* __restrict__ kin,
                  const float* __restrict__ Wq, const float* __restrict__ Wk,
                  ushort* __restrict__ XQ1, ushort* __restrict__ XQ2, ushort* __restrict__ XQ3,
                  ushort* __restrict__ XK1, ushort* __restrict__ XK2, ushort* __restrict__ XK3,
                  ushort* __restrict__ W1, ushort* __restrict__ W2, ushort* __restrict__ W3)
{
    const int z = blockIdx.y;
    const int gid = blockIdx.x * 256 + threadIdx.x;
    const float* src;
    ushort *O1, *O2, *O3;
    size_t dst, soff;
    if (z < 2) {
        int m = gid >> 6, c = gid & 63;
        int b = (m >= N) ? 1 : 0;
        int npos = m - b * N;
        src = z ? kin : qin;
        if (z) { O1 = XK1; O2 = XK2; O3 = XK3; }
        else   { O1 = XQ1; O2 = XQ2; O3 = XQ3; }
        soff = (size_t)m * D + c * 8;
        dst = ((size_t)(b * 8 + (c >> 3)) * N + npos) * 64 + (c & 7) * 8;
    } else {
        if (gid >= 65536) return;
        int r = gid >> 6, c = gid & 63;
        int inp = r >> 9, n = r & 511;
        src = inp ? Wk : Wq;
        O1 = W1; O2 = W2; O3 = W3;
        soff = (size_t)n * D + c * 8;
        dst = ((size_t)(inp * 8 + (c >> 3)) * 512 + n) * 64 + (c & 7) * 8;
    }
    ushort8v u1, u2, u3;
    #pragma unroll
    for (int j = 0; j < 8; j++) {
        U3 t = split3(src[soff + j]);
        u1[j] = t.a; u2[j] = t.b; u3[j] = t.c;
    }
    *(ushort8v*)&O1[dst] = u1;
    *(ushort8v*)&O2[dst] = u2;
    *(ushort8v*)&O3[dst] = u3;
}

// ---------------------------------------------------------------------------
// Kernel A: MFMA projection (3-split, 6 products).  Async LDS staging.
// ---------------------------------------------------------------------------
__global__ __launch_bounds__(256)
void proj_kernel(const ushort* __restrict__ X1, const ushort* __restrict__ X2,
                 const ushort* __restrict__ X3, const ushort* __restrict__ Wp1,
                 const ushort* __restrict__ Wp2, const ushort* __restrict__ Wp3,
                 const float* __restrict__ bias,
                 ushort* __restrict__ O1, ushort* __restrict__ O2, ushort* __restrict__ O3)
{
    const int tid = threadIdx.x;
    const int lane = tid & 63, w = tid >> 6;
    const int wm = w >> 1, wn = w & 1;
    const int lg = lane >> 4, ln = lane & 15;
    const int hsel = blockIdx.x;          // head 0..7
    const int my = blockIdx.y;            // 0..71
    const int b = my / 36;
    const int npos0 = (my % 36) * 64;

    __shared__ alignas(16) ushort bufX[3][64 * 64];
    __shared__ alignas(16) ushort bufW[3][64 * 64];

    f32x4 acc[2][2];
    #pragma unroll
    for (int mt = 0; mt < 2; mt++)
        #pragma unroll
        for (int nt = 0; nt < 2; nt++) acc[mt][nt] = (f32x4){0.f, 0.f, 0.f, 0.f};

    for (int kh = 0; kh < 8; kh++) {
        stage_async(bufX[0], X1 + ((size_t)(b * 8 + kh) * N + npos0) * 64, tid);
        stage_async(bufX[1], X2 + ((size_t)(b * 8 + kh) * N + npos0) * 64, tid);
        stage_async(bufX[2], X3 + ((size_t)(b * 8 + kh) * N + npos0) * 64, tid);
        stage_async(bufW[0], Wp1 + ((size_t)kh * 512 + hsel * 64) * 64, tid);
        stage_async(bufW[1], Wp2 + ((size_t)kh * 512 + hsel * 64) * 64, tid);
        stage_async(bufW[2], Wp3 + ((size_t)kh * 512 + hsel * 64) * 64, tid);
        __syncthreads();

        short8 A[3][2][2], Bv[3][2][2];
        #pragma unroll
        for (int mt = 0; mt < 2; mt++)
            #pragma unroll
            for (int c = 0; c < 2; c++) {
                int row = 32 * wm + 16 * mt + ln, k = 32 * c + 8 * lg;
                A[0][mt][c] = frag_swz(bufX[0], row, k);
                A[1][mt][c] = frag_swz(bufX[1], row, k);
                A[2][mt][c] = frag_swz(bufX[2], row, k);
            }
        #pragma unroll
        for (int nt = 0; nt < 2; nt++)
            #pragma unroll
            for (int c = 0; c < 2; c++) {
                int row = 32 * wn + 16 * nt + ln, k = 32 * c + 8 * lg;
                Bv[0][nt][c] = frag_swz(bufW[0], row, k);
                Bv[1][nt][c] = frag_swz(bufW[1], row, k);
                Bv[2][nt][c] = frag_swz(bufW[2], row, k);
            }
        #pragma unroll
        for (int mt = 0; mt < 2; mt++)
            #pragma unroll
            for (int nt = 0; nt < 2; nt++) {
                f32x4 a = acc[mt][nt];
                a = MFMA(A[0][mt][0], Bv[0][nt][0], a);
                a = MFMA(A[0][mt][1], Bv[0][nt][1], a);
                a = MFMA(A[0][mt][0], Bv[1][nt][0], a);
                a = MFMA(A[0][mt][1], Bv[1][nt][1], a);
                a = MFMA(A[1][mt][0], Bv[0][nt][0], a);
                a = MFMA(A[1][mt][1], Bv[0][nt][1], a);
                a = MFMA(A[0][mt][0], Bv[2][nt][0], a);
                a = MFMA(A[0][mt][1], Bv[2][nt][1], a);
                a = MFMA(A[1][mt][0], Bv[1][nt][0], a);
                a = MFMA(A[1][mt][1], Bv[1][nt][1], a);
                a = MFMA(A[2][mt][0], Bv[0][nt][0], a);
                a = MFMA(A[2][mt][1], Bv[0][nt][1], a);
                acc[mt][nt] = a;
            }
        __syncthreads();
    }
    // epilogue: stage C through LDS, re-split3, coalesced per-head writes
    float* Cs = (float*)&bufX[0][0];      // [64][68]
    #pragma unroll
    for (int mt = 0; mt < 2; mt++)
        #pragma unroll
        for (int nt = 0; nt < 2; nt++)
            #pragma unroll
            for (int r = 0; r < 4; r++)
                Cs[(32 * wm + 16 * mt + 4 * lg + r) * 68 + 32 * wn + 16 * nt + ln] =
                    acc[mt][nt][r];
    __syncthreads();
    const int row = tid >> 2, c0 = (tid & 3) * 16;
    size_t dst = ((size_t)(b * 8 + hsel) * N + npos0 + row) * 64 + c0;
    #pragma unroll
    for (int half = 0; half < 2; half++) {
        ushort8v u1, u2, u3;
        #pragma unroll
        for (int j = 0; j < 8; j++) {
            int cc = c0 + half * 8 + j;
            float v = Cs[row * 68 + cc] + bias[hsel * 64 + cc];
            U3 t = split3(v);
            u1[j] = t.a; u2[j] = t.b; u3[j] = t.c;
        }
        *(ushort8v*)&O1[dst + half * 8] = u1;
        *(ushort8v*)&O2[dst + half * 8] = u2;
        *(ushort8v*)&O3[dst + half * 8] = u3;
    }
}

// ---------------------------------------------------------------------------
// Kernel B: argmax.  Block = 128 resident keys (4 waves x 32, frags in regs);
// streams 64-q tiles via async LDS staging (single buffer, 2 barriers/tile).
// 6 products.  grid (18, 16, 6).  Tie-break: lowest q.
// ---------------------------------------------------------------------------
__global__ __launch_bounds__(256)
void argmax_kernel(const ushort* __restrict__ Q1, const ushort* __restrict__ Q2,
                   const ushort* __restrict__ Q3, const ushort* __restrict__ K1,
                   const ushort* __restrict__ K2, const ushort* __restrict__ K3,
                   float* __restrict__ argV, int* __restrict__ argQ)
{
    const int bh = blockIdx.y;
    const int g  = blockIdx.z;
    const int tid = threadIdx.x;
    const int w = tid >> 6, lane = tid & 63;
    const int lg = lane >> 4, ln = lane & 15;
    const int kb = blockIdx.x * 128 + w * 32;   // wave's 32-key base
    const size_t hb = (size_t)bh * N;

    __shared__ alignas(16) ushort buf[3][64 * 64];

    short8 A[3][2][2];                    // [comp][mt][c], resident keys
    #pragma unroll
    for (int mt = 0; mt < 2; mt++)
        #pragma unroll
        for (int c = 0; c < 2; c++) {
            size_t off = (hb + kb + 16 * mt + ln) * 64 + 32 * c + 8 * lg;
            A[0][mt][c] = gfrag(K1, off);
            A[1][mt][c] = gfrag(K2, off);
            A[2][mt][c] = gfrag(K3, off);
        }

    float bestv[2][4];
    int   bestq[2][4];
    #pragma unroll
    for (int mt = 0; mt < 2; mt++)
        #pragma unroll
        for (int r = 0; r < 4; r++) { bestv[mt][r] = -3e38f; bestq[mt][r] = 0; }

    for (int qt = g * CH_ARG; qt < (g + 1) * CH_ARG; qt += 64) {
        stage_async(buf[0], Q1 + (hb + qt) * 64, tid);
        stage_async(buf[1], Q2 + (hb + qt) * 64, tid);
        stage_async(buf[2], Q3 + (hb + qt) * 64, tid);
        __syncthreads();
        #pragma unroll
        for (int nt = 0; nt < 4; nt++) {
            short8 Bv0[2], Bv1[2], Bv2[2];
            #pragma unroll
            for (int c = 0; c < 2; c++) {
                int row = 16 * nt + ln, k = 32 * c + 8 * lg;
                Bv0[c] = frag_swz(buf[0], row, k);
                Bv1[c] = frag_swz(buf[1], row, k);
                Bv2[c] = frag_swz(buf[2], row, k);
            }
            const int q = qt + 16 * nt + ln;
            #pragma unroll
            for (int mt = 0; mt < 2; mt++) {
                f32x4 acc = {0.f, 0.f, 0.f, 0.f};
                acc = MFMA(A[0][mt][0], Bv0[0], acc);
                acc = MFMA(A[0][mt][1], Bv0[1], acc);
                acc = MFMA(A[0][mt][0], Bv1[0], acc);
                acc = MFMA(A[0][mt][1], Bv1[1], acc);
                acc = MFMA(A[1][mt][0], Bv0[0], acc);
                acc = MFMA(A[1][mt][1], Bv0[1], acc);
                acc = MFMA(A[0][mt][0], Bv2[0], acc);
                acc = MFMA(A[0][mt][1], Bv2[1], acc);
                acc = MFMA(A[1][mt][0], Bv1[0], acc);
                acc = MFMA(A[1][mt][1], Bv1[1], acc);
                acc = MFMA(A[2][mt][0], Bv0[0], acc);
                acc = MFMA(A[2][mt][1], Bv0[1], acc);
                #pragma unroll
                for (int r = 0; r < 4; r++)
                    if (acc[r] > bestv[mt][r]) { bestv[mt][r] = acc[r]; bestq[mt][r] = q; }
            }
        }
        __syncthreads();
    }
    // reduce over the 16 q-lanes (ln); tie -> lower q
    #pragma unroll
    for (int d = 1; d < 16; d <<= 1) {
        #pragma unroll
        for (int mt = 0; mt < 2; mt++)
            #pragma unroll
            for (int r = 0; r < 4; r++) {
                float ov = __shfl_xor(bestv[mt][r], d);
                int   oq = __shfl_xor(bestq[mt][r], d);
                if (ov > bestv[mt][r] || (ov == bestv[mt][r] && oq < bestq[mt][r])) {
                    bestv[mt][r] = ov; bestq[mt][r] = oq;
                }
            }
    }
    if (ln == 0) {
        #pragma unroll
        for (int mt = 0; mt < 2; mt++)
            #pragma unroll
            for (int r = 0; r < 4; r++) {
                size_t o = (size_t)g * BHN + hb + kb + 16 * mt + 4 * lg + r;
                argV[o] = bestv[mt][r];
                argQ[o] = bestq[mt][r];
            }
    }
}

// ---------------------------------------------------------------------------
// Kernel C: row pass.  Block = 128 resident queries (4 waves x 32, B-frags in
// regs); streams 64-key tiles via async LDS staging (single buffer).  Side
// arrays preloaded once per chunk WITH inline argmax-combine (ascending g,
// strict >, lowest-q tie-break).  grid (18, 16, 6).
// ---------------------------------------------------------------------------
__global__ __launch_bounds__(256)
void rowpass_kernel(const ushort* __restrict__ Q1, const ushort* __restrict__ Q2,
                    const ushort* __restrict__ K1, const ushort* __restrict__ K2,
                    const float* __restrict__ argV, const int* __restrict__ argQ,
                    const float* __restrict__ value0,
                    float* __restrict__ rowPl, float* __restrict__ rowPa)
{
    const int bh = blockIdx.y, b = bh >> 3;
    const int g = blockIdx.z;
    const int tid = threadIdx.x;
    const int w = tid >> 6, lane = tid & 63;
    const int lg = lane >> 4, ln = lane & 15;
    const int qb = blockIdx.x * 128 + w * 32;   // wave's 32-query base
    const size_t hb = (size_t)bh * N;
    const int kbase = g * CH_RC;

    __shared__ alignas(16) ushort buf[2][64 * 64];
    __shared__ float F[48][49];
    __shared__ int ixi[CH_RC], iyi[CH_RC];
    __shared__ float v0s[CH_RC];

    for (int i = tid; i < 48 * 48; i += 256) {
        int a = i / 48, j = i % 48;
        float lj = -1.0f + (2.0f / 47.0f) * (float)j;
        float dd = lj - (float)a;
        F[a][j] = __expf(-dd * dd * INV2S2) * FC;
    }
    for (int i = tid; i < CH_RC; i += 256) {
        size_t key = hb + kbase + i;
        float bv = argV[key]; int bq = argQ[key];
        #pragma unroll
        for (int g2 = 1; g2 < G_ARG; g2++) {
            float v = argV[(size_t)g2 * BHN + key];
            int   q = argQ[(size_t)g2 * BHN + key];
            if (v > bv) { bv = v; bq = q; }
        }
        ixi[i] = bq % 48; iyi[i] = bq / 48;
        v0s[i] = value0[(size_t)b * N + kbase + i];
    }

    short8 Bq[2][2][2];                   // [comp][nt][c], resident queries
    int qx_[2], qy_[2];
    #pragma unroll
    for (int nt = 0; nt < 2; nt++) {
        #pragma unroll
        for (int c = 0; c < 2; c++) {
            size_t off = (hb + qb + 16 * nt + ln) * 64 + 32 * c + 8 * lg;
            Bq[0][nt][c] = gfrag(Q1, off);
            Bq[1][nt][c] = gfrag(Q2, off);
        }
        int qq = qb + 16 * nt + ln;
        qx_[nt] = qq % 48; qy_[nt] = qq / 48;
    }

    float l[2] = {0.f, 0.f}, a0[2] = {0.f, 0.f};

    for (int t = 0; t < CH_RC / 64; ++t) {
        stage_async(buf[0], K1 + (hb + kbase + t * 64) * 64, tid);
        stage_async(buf[1], K2 + (hb + kbase + t * 64) * 64, tid);
        __syncthreads();
        #pragma unroll
        for (int mt = 0; mt < 4; mt++) {
            short8 A0[2], A1[2];
            #pragma unroll
            for (int c = 0; c < 2; c++) {
                int row = 16 * mt + ln, k = 32 * c + 8 * lg;
                A0[c] = frag_swz(buf[0], row, k);
                A1[c] = frag_swz(buf[1], row, k);
            }
            #pragma unroll
            for (int nt = 0; nt < 2; nt++) {
                f32x4 acc = {0.f, 0.f, 0.f, 0.f};
                acc = MFMA(A0[0], Bq[0][nt][0], acc);
                acc = MFMA(A0[1], Bq[0][nt][1], acc);
                acc = MFMA(A0[0], Bq[1][nt][0], acc);
                acc = MFMA(A0[1], Bq[1][nt][1], acc);
                acc = MFMA(A1[0], Bq[0][nt][0], acc);
                acc = MFMA(A1[1], Bq[0][nt][1], acc);
                #pragma unroll
                for (int r = 0; r < 4; r++) {
                    int koff = t * 64 + 16 * mt + 4 * lg + r;
                    float tt = acc[r] * F[ixi[koff]][qx_[nt]] * F[iyi[koff]][qy_[nt]];
                    float e = __builtin_amdgcn_exp2f(tt);
                    l[nt]  += e;
                    a0[nt] += e * v0s[koff];
                }
            }
        }
        __syncthreads();
    }
    // sum over the 4 lg key-groups within the wave
    #pragma unroll
    for (int d = 16; d < 64; d <<= 1) {
        #pragma unroll
        for (int nt = 0; nt < 2; nt++) {
            l[nt]  += __shfl_xor(l[nt], d);
            a0[nt] += __shfl_xor(a0[nt], d);
        }
    }
    if (lane < 16) {
        #pragma unroll
        for (int nt = 0; nt < 2; nt++) {
            size_t o = (size_t)g * BHN + hb + qb + 16 * nt + ln;
            rowPl[o] = l[nt];
            rowPa[o] = a0[nt];
        }
    }
}

// rowfinal: den = sum_g l;  x0 = (sum_g a0) / den.
__global__ __launch_bounds__(256)
void rowfinal_kernel(const float* __restrict__ rowPl, const float* __restrict__ rowPa,
                     float* __restrict__ denomo, float* __restrict__ x0o)
{
    int i = blockIdx.x * 256 + threadIdx.x;
    if (i >= BHN) return;
    float L = 0.f, A = 0.f;
    #pragma unroll
    for (int g = 0; g < G_RC; g++) {
        L += rowPl[(size_t)g * BHN + i];
        A += rowPa[(size_t)g * BHN + i];
    }
    denomo[i] = L;
    x0o[i] = A / L;
}

// ---------------------------------------------------------------------------
// Kernel D: column pass.  Block = 128 resident keys (4 waves x 32, A-frags in
// regs); streams 64-q tiles via async LDS staging (single buffer).  Side
// arrays preloaded once per chunk; resident-key idx combined inline.
// grid (18, 16, 6).
// ---------------------------------------------------------------------------
__global__ __launch_bounds__(256)
void colpass_kernel(const ushort* __restrict__ Q1, const ushort* __restrict__ Q2,
                    const ushort* __restrict__ K1, const ushort* __restrict__ K2,
                    const float* __restrict__ argV, const int* __restrict__ argQ,
                    const float* __restrict__ value1,
                    const float* __restrict__ denomo, float* __restrict__ colP)
{
    const int bh = blockIdx.y, b = bh >> 3;
    const int g = blockIdx.z;
    const int tid = threadIdx.x;
    const int w = tid >> 6, lane = tid & 63;
    const int lg = lane >> 4, ln = lane & 15;
    const int kb = blockIdx.x * 128 + w * 32;   // wave's 32-key base
    const size_t hb = (size_t)bh * N;
    const int qbase = g * CH_RC;

    __shared__ alignas(16) ushort buf[2][64 * 64];
    __shared__ float F[48][49];
    __shared__ float wvs[CH_RC];
    __shared__ int qxs[CH_RC], qys[CH_RC];

    for (int i = tid; i < 48 * 48; i += 256) {
        int a = i / 48, j = i % 48;
        float lj = -1.0f + (2.0f / 47.0f) * (float)j;
        float dd = lj - (float)a;
        F[a][j] = __expf(-dd * dd * INV2S2) * FC;
    }
    for (int i = tid; i < CH_RC; i += 256) {
        int qg = qbase + i;
        wvs[i] = value1[(size_t)b * N + qg] / denomo[hb + qg];
        qxs[i] = qg % 48; qys[i] = qg / 48;
    }

    short8 A[2][2][2];                    // [comp][mt][c], resident keys
    int ixr[2][4], iyr[2][4];
    #pragma unroll
    for (int mt = 0; mt < 2; mt++) {
        #pragma unroll
        for (int c = 0; c < 2; c++) {
            size_t off = (hb + kb + 16 * mt + ln) * 64 + 32 * c + 8 * lg;
            A[0][mt][c] = gfrag(K1, off);
            A[1][mt][c] = gfrag(K2, off);
        }
        #pragma unroll
        for (int r = 0; r < 4; r++) {
            size_t key = hb + kb + 16 * mt + 4 * lg + r;
            float bv = argV[key]; int bq = argQ[key];
            #pragma unroll
            for (int g2 = 1; g2 < G_ARG; g2++) {
                float v = argV[(size_t)g2 * BHN + key];
                int   q = argQ[(size_t)g2 * BHN + key];
                if (v > bv) { bv = v; bq = q; }
            }
            ixr[mt][r] = bq % 48; iyr[mt][r] = bq / 48;
        }
    }

    float acc1[2][4] = {};

    for (int t = 0; t < CH_RC / 64; ++t) {
        stage_async(buf[0], Q1 + (hb + qbase + t * 64) * 64, tid);
        stage_async(buf[1], Q2 + (hb + qbase + t * 64) * 64, tid);
        __syncthreads();
        #pragma unroll
        for (int nt = 0; nt < 4; nt++) {
            short8 B0[2], B1[2];
            #pragma unroll
            for (int c = 0; c < 2; c++) {
                int row = 16 * nt + ln, k = 32 * c + 8 * lg;
                B0[c] = frag_swz(buf[0], row, k);
                B1[c] = frag_swz(buf[1], row, k);
            }
            const int qoff = t * 64 + 16 * nt + ln;
            const int qx = qxs[qoff], qy = qys[qoff];
            const float wv = wvs[qoff];
            #pragma unroll
            for (int mt = 0; mt < 2; mt++) {
                f32x4 acc = {0.f, 0.f, 0.f, 0.f};
                acc = MFMA(A[0][mt][0], B0[0], acc);
                acc = MFMA(A[0][mt][1], B0[1], acc);
                acc = MFMA(A[0][mt][0], B1[0], acc);
                acc = MFMA(A[0][mt][1], B1[1], acc);
                acc = MFMA(A[1][mt][0], B0[0], acc);
                acc = MFMA(A[1][mt][1], B0[1], acc);
                #pragma unroll
                for (int r = 0; r < 4; r++) {
                    float tt = acc[r] * F[ixr[mt][r]][qx] * F[iyr[mt][r]][qy];
                    acc1[mt][r] += __builtin_amdgcn_exp2f(tt) * wv;
                }
            }
        }
        __syncthreads();
    }
    // sum over the 16 q-lanes (ln)
    #pragma unroll
    for (int d = 1; d < 16; d <<= 1)
        #pragma unroll
        for (int mt = 0; mt < 2; mt++)
            #pragma unroll
            for (int r = 0; r < 4; r++)
                acc1[mt][r] += __shfl_xor(acc1[mt][r], d);
    if (ln == 0) {
        #pragma unroll
        for (int mt = 0; mt < 2; mt++)
            #pragma unroll
            for (int r = 0; r < 4; r++)
                colP[(size_t)g * BHN + hb + kb + 16 * mt + 4 * lg + r] = acc1[mt][r];
    }
}

// colfinal: x1 = sum_g partials.
__global__ __launch_bounds__(256)
void colfinal_kernel(const float* __restrict__ colP, float* __restrict__ x1o)
{
    int i = blockIdx.x * 256 + threadIdx.x;
    if (i >= BHN) return;
    float X = 0.f;
    #pragma unroll
    for (int g = 0; g < G_RC; g++) X += colP[(size_t)g * BHN + i];
    x1o[i] = X;
}

// ---------------------------------------------------------------------------
// Kernel E: out[b,q,k] = (1/8) * sum_h x0[b,h,q] * x1[b,h,k]   (float4 stores)
// ---------------------------------------------------------------------------
__global__ __launch_bounds__(256)
void outer_kernel(const float* __restrict__ x0, const float* __restrict__ x1,
                  float* __restrict__ out)
{
    const int b = blockIdx.z;
    const int q0 = blockIdx.y * 32, k0 = blockIdx.x * 32;
    __shared__ float x0s[8][32];
    __shared__ float x1s[8][32];
    const int tid = threadIdx.x;
    {
        int hh = tid >> 5, i = tid & 31;
        x0s[hh][i] = x0[(size_t)(b * 8 + hh) * N + q0 + i];
        x1s[hh][i] = x1[(size_t)(b * 8 + hh) * N + k0 + i];
    }
    __syncthreads();
    const int row = tid >> 3, c4 = (tid & 7) * 4;
    float4 a = {0.f, 0.f, 0.f, 0.f};
    #pragma unroll
    for (int hh = 0; hh < 8; hh++) {
        float s = x0s[hh][row];
        a.x += s * x1s[hh][c4 + 0];
        a.y += s * x1s[hh][c4 + 1];
        a.z += s * x1s[hh][c4 + 2];
        a.w += s * x1s[hh][c4 + 3];
    }
    a.x *= 0.125f; a.y *= 0.125f; a.z *= 0.125f; a.w *= 0.125f;
    *(float4*)(out + (size_t)b * N * N + (size_t)(q0 + row) * N + k0 + c4) = a;
}

} // namespace

extern "C" void kernel_launch(void* const* d_in, const int* in_sizes, int n_in,
                              void* d_out, int out_size, void* d_ws, size_t ws_size,
                              hipStream_t stream) {
    const float* qin = (const float*)d_in[0];
    const float* kin = (const float*)d_in[1];
    const float* v0  = (const float*)d_in[2];
    const float* v1  = (const float*)d_in[3];
    const float* Wq  = (const float*)d_in[4];
    const float* bq  = (const float*)d_in[5];
    const float* Wk  = (const float*)d_in[6];
    const float* bk  = (const float*)d_in[7];
    float* out = (float*)d_out;

    // d_out = exactly 9 split-array slots (18*ARR bytes = out bytes):
    //   A.1 [0,3ARR)   : Q1..Q3 proj outputs (live to colpass)
    //   A.2 [3ARR,6ARR): Xk input splits (dead after projK) -> partials/den
    //   B   [6ARR,9ARR): Xq input splits (dead after projQ) -> K1..K3 outputs
    const size_t ARR = (size_t)BH * N * DK;   // 2359296 ushorts
    ushort* out_u = (ushort*)d_out;
    ushort* Q1  = out_u;
    ushort* Q2  = out_u + ARR;
    ushort* Q3  = out_u + 2 * ARR;
    ushort* XK1 = out_u + 3 * ARR;
    ushort* XK2 = out_u + 4 * ARR;
    ushort* XK3 = out_u + 5 * ARR;
    ushort* XQ1 = out_u + 6 * ARR;
    ushort* XQ2 = out_u + 7 * ARR;
    ushort* XQ3 = out_u + 8 * ARR;
    ushort* K1 = XQ1;  ushort* K2 = XQ2;  ushort* K3 = XQ3;  // projK overwrites Xq

    float* tail = (float*)XK1;                 // A.2 reuse after projK (14.15 MB)
    float* argV  = tail;                                  // [G_ARG][BHN]
    int*   argQ  = (int*)(argV + (size_t)G_ARG * BHN);    // [G_ARG][BHN]
    float* rowPl = (float*)(argQ + (size_t)G_ARG * BHN);  // [G_RC][BHN]
    float* rowPa = rowPl + (size_t)G_RC * BHN;            // [G_RC][BHN]
    float* colP  = rowPa + (size_t)G_RC * BHN;            // [G_RC][BHN]
    float* den   = colP + (size_t)G_RC * BHN;             // [BHN]

    // ws: W splits (3 MB) + x0/x1 (outer's inputs; must not live in d_out)
    const size_t WARR = (size_t)2 * 512 * 512;     // 524288 ushorts per comp
    ushort* W1 = (ushort*)d_ws;
    ushort* W2 = W1 + WARR;
    ushort* W3 = W2 + WARR;
    float* x0b = (float*)(W3 + WARR);
    float* x1b = x0b + (size_t)BHN;

    const size_t WSLICE = (size_t)8 * 512 * 64;    // per-input W-split stride

    const int RB = (BHN + 255) / 256;   // 144 blocks for elementwise finalizers

    split_kernel   <<<dim3(1152, 3),       dim3(256), 0, stream>>>(qin, kin, Wq, Wk,
                                                                   XQ1, XQ2, XQ3,
                                                                   XK1, XK2, XK3,
                                                                   W1, W2, W3);
    proj_kernel    <<<dim3(8, 72),         dim3(256), 0, stream>>>(XQ1, XQ2, XQ3,
                                                                   W1, W2, W3, bq,
                                                                   Q1, Q2, Q3);
    proj_kernel    <<<dim3(8, 72),         dim3(256), 0, stream>>>(XK1, XK2, XK3,
                                                                   W1 + WSLICE, W2 + WSLICE,
                                                                   W3 + WSLICE, bk,
                                                                   K1, K2, K3);
    argmax_kernel  <<<dim3(18, 16, G_ARG), dim3(256), 0, stream>>>(Q1, Q2, Q3, K1, K2, K3,
                                                                   argV, argQ);
    rowpass_kernel <<<dim3(18, 16, G_RC),  dim3(256), 0, stream>>>(Q1, Q2, K1, K2,
                                                                   argV, argQ, v0,
                                                                   rowPl, rowPa);
    rowfinal_kernel<<<dim3(RB),            dim3(256), 0, stream>>>(rowPl, rowPa, den, x0b);
    colpass_kernel <<<dim3(18, 16, G_RC),  dim3(256), 0, stream>>>(Q1, Q2, K1, K2,
                                                                   argV, argQ, v1,
                                                                   den, colP);
    colfinal_kernel<<<dim3(RB),            dim3(256), 0, stream>>>(colP, x1b);
    outer_kernel   <<<dim3(72, 72, 2),     dim3(256), 0, stream>>>(x0b, x1b, out);
}